// Round 12
// baseline (768.612 us; speedup 1.0000x reference)
//
#include <hip/hip_runtime.h>
#include <hip/hip_bf16.h>
#include <cstdint>

typedef unsigned long long u64;
typedef unsigned int u32;
typedef unsigned short u16;

constexpr int NB   = 8;     // batch
constexpr int NL   = 4096;  // H*W
constexpr int ND   = 192;   // D_INNER
constexpr int NDM  = 96;    // D_MODEL
constexpr int NE   = 8064;  // edges per batch
constexpr int NEH  = 4032;  // horizontal edges
constexpr int SENT = 8190;  // Euler sentinel (m = 2*4095)

__device__ __forceinline__ float siluf(float x){ return x / (1.f + expf(-x)); }
__device__ __forceinline__ float softplusf(float x){ return fmaxf(x,0.f) + log1pf(expf(-fabsf(x))); }

// single-wave LDS-only fence: wave LDS ops complete in order; drain lgkm + compiler barrier.
__device__ __forceinline__ void lds_fence_wave(){
  asm volatile("s_waitcnt lgkmcnt(0)" ::: "memory");
}
__device__ __forceinline__ void compiler_fence(){
  asm volatile("" ::: "memory");
}

__device__ __forceinline__ float wred_f(float v){
  #pragma unroll
  for (int o=32;o;o>>=1) v += __shfl_down(v,o);
  return __shfl(v,0);
}
__device__ __forceinline__ double wred_d(double v){
  #pragma unroll
  for (int o=32;o;o>>=1) v += __shfl_down(v,o);
  return __shfl(v,0);
}

// edge e -> endpoints (reference ordering: horizontal first, row-major, then vertical); u < v always
__device__ __forceinline__ void edge_uv(int e, int& u, int& v){
  if (e < NEH){ int r=e/63; int c=e-r*63; u=(r<<6)+c; v=u+1; }
  else        { u=e-NEH; v=u+64; }
}

__device__ __forceinline__ void amin64(u64* addr, u64 val){
  u64 old = *addr;
  while (val < old){
    u64 assumed = old;
    old = atomicCAS(addr, assumed, val);
    if (old == assumed) break;
  }
}

// ---------------- K1: xz = x @ in_proj_w.T (f32, LDS-tiled); split -> xc_pre, z=silu ----------------
__global__ __launch_bounds__(256) void k1_inproj(const float* __restrict__ x, const float* __restrict__ w,
                                                 float* __restrict__ xc_pre, float* __restrict__ zb){
  __shared__ float sx[96*33];       // [k][row0..31], pad 33
  __shared__ float sw[96*97];       // [k][col0..95], pad 97
  const int tid = threadIdx.x;
  const int brow = blockIdx.x >> 2;
  const int cc   = blockIdx.x & 3;
  const int row0 = brow * 32;
  {
    const float* src = x + (size_t)row0*96;
    for (int i=tid; i<32*96; i+=256){
      int r = i/96, k = i - r*96;
      sx[k*33 + r] = src[i];
    }
  }
  {
    const float* src = w + (size_t)cc*96*96;
    for (int i=tid; i<96*96; i+=256){
      int c = i/96, k = i - c*96;
      sw[k*97 + c] = src[i];
    }
  }
  __syncthreads();
  const int rq = tid >> 5;
  const int cq = tid & 31;
  float acc[4][3];
  #pragma unroll
  for (int a=0;a<4;++a)
    #pragma unroll
    for (int bcl=0;bcl<3;++bcl) acc[a][bcl] = 0.f;
  #pragma unroll 4
  for (int k=0;k<96;++k){
    float4 xa = *(const float4*)&sx[k*33 + rq*4];
    float w0 = sw[k*97 + cq*3 + 0];
    float w1 = sw[k*97 + cq*3 + 1];
    float w2 = sw[k*97 + cq*3 + 2];
    acc[0][0] += xa.x*w0; acc[0][1] += xa.x*w1; acc[0][2] += xa.x*w2;
    acc[1][0] += xa.y*w0; acc[1][1] += xa.y*w1; acc[1][2] += xa.y*w2;
    acc[2][0] += xa.z*w0; acc[2][1] += xa.z*w1; acc[2][2] += xa.z*w2;
    acc[3][0] += xa.w*w0; acc[3][1] += xa.w*w1; acc[3][2] += xa.w*w2;
  }
  #pragma unroll
  for (int a=0;a<4;++a){
    size_t row = row0 + rq*4 + a;
    #pragma unroll
    for (int bcl=0;bcl<3;++bcl){
      int c = cq*3 + bcl;
      float v = acc[a][bcl];
      if (cc < 2) xc_pre[row*ND + cc*96 + c] = v;
      else        zb[row*ND + (cc-2)*96 + c] = siluf(v);
    }
  }
}

// ---------------- K2: depthwise 3x3 conv (SAME) + bias + silu (f32) -> xs ----------------
__global__ __launch_bounds__(256) void k2_conv(const float* __restrict__ xc_pre, const float* __restrict__ cw,
                                               const float* __restrict__ cb, float* __restrict__ xs){
  int idx = blockIdx.x*256 + threadIdx.x;
  if (idx >= NB*NL*ND) return;
  int d = idx % ND;
  int l = (idx/ND) & 4095;
  int b = idx / (ND*NL);
  int r = l >> 6, c = l & 63;
  float acc = cb[d];
  #pragma unroll
  for (int dy=-1; dy<=1; ++dy){
    int rr = r+dy; if (rr<0 || rr>63) continue;
    #pragma unroll
    for (int dx=-1; dx<=1; ++dx){
      int cc = c+dx; if (cc<0 || cc>63) continue;
      acc += xc_pre[((size_t)b*NL + (rr<<6) + cc)*ND + d] * cw[d*9 + (dy+1)*3 + (dx+1)];
    }
  }
  xs[idx] = siluf(acc);
}

// ---------------- K3: x_dbl dots, dts->softplus, ew/BX written CHANNEL-MAJOR, Cs, f64 norms ----------------
__global__ __launch_bounds__(256) void k3_ssm(const float* __restrict__ xs, const float* __restrict__ xpw,
                                              const float* __restrict__ dtw, const float* __restrict__ dtb,
                                              const float* __restrict__ alog,
                                              float* __restrict__ ew_cm, float* __restrict__ up_cm,
                                              float* __restrict__ Cs, double* __restrict__ norms){
  int gid = blockIdx.x*4 + (threadIdx.x>>6);   // one wave per (b,l)
  if (gid >= NB*NL) return;
  int lane = threadIdx.x & 63;
  int b = gid >> 12, l = gid & 4095;
  const float* xr = xs + (size_t)gid*ND;
  float xv[3];
  #pragma unroll
  for (int j=0;j<3;++j) xv[j] = xr[lane + 64*j];
  float sums[8];
  #pragma unroll
  for (int cc=0; cc<8; ++cc){
    float p = 0.f;
    #pragma unroll
    for (int j=0;j<3;++j) p += xv[j]*xpw[cc*ND + lane + 64*j];
    sums[cc] = wred_f(p);
  }
  double n2 = 0.0;
  #pragma unroll
  for (int j=0;j<3;++j) n2 += (double)xv[j]*(double)xv[j];
  n2 = wred_d(n2);
  if (lane==0){
    Cs[gid] = sums[7];
    norms[gid] = fmax(sqrt(n2), 1e-8);
  }
  float Bv = sums[6];
  #pragma unroll
  for (int j=0;j<3;++j){
    int d = lane + 64*j;
    float dtv = dtb[d];
    #pragma unroll
    for (int r=0;r<6;++r) dtv += sums[r]*dtw[d*6+r];
    float sp = softplusf(dtv);
    float A  = -expf(alog[d]);
    size_t o = ((size_t)(b*ND + d))*NL + l;      // channel-major
    ew_cm[o] = expf(sp*A);
    up_cm[o] = sp*Bv*xv[j];   // BX = dts*Bs*xs
  }
}

// ---------------- K4: per-edge f64 normalized dot -> sortable u64 key ----------------
__global__ __launch_bounds__(256) void k4_keys(const float* __restrict__ xs, const double* __restrict__ norms,
                                               u64* __restrict__ keys){
  int gid = blockIdx.x*4 + (threadIdx.x>>6);   // one wave per (b,e)
  if (gid >= NB*NE) return;
  int lane = threadIdx.x & 63;
  int b = gid / NE, e = gid - b*NE;
  int u, v; edge_uv(e, u, v);
  const float* xu = xs + ((size_t)(b*NL + u))*ND;
  const float* xw = xs + ((size_t)(b*NL + v))*ND;
  double nu = norms[b*NL+u], nv = norms[b*NL+v];
  double dot = 0.0;
  #pragma unroll
  for (int j=0;j<3;++j){
    int d = lane + 64*j;
    double du = (double)xu[d] / nu;     // fn = f/norm per element, like reference
    double dv = (double)xw[d] / nv;
    dot += du*dv;
  }
  dot = wred_d(dot);
  if (lane==0){
    long long q = __double2ll_rn((1.0 - dot) * 17592186044416.0);  // 2^44
    if (q < 0) q = 0;
    keys[gid] = (((u64)q) << 13) | (u64)e;
  }
}

// ---------------- K5: Boruvka MST + Euler-tour depth/parent (single Wyllie + positional scan) ----------------
__global__ __launch_bounds__(1024) void k5_tree(const u64* __restrict__ keys,
                                                int* __restrict__ meta_g, u16* __restrict__ meta2_g,
                                                int* __restrict__ level_start_g,
                                                int* __restrict__ maxd_g, int* __restrict__ lmin_g){
  const int b = blockIdx.x;
  const int tid = threadIdx.x;
  __shared__ u64 s_best[4096];           // 32 KB ; later: arr u32[8192] (packed succ|dist) / pfx short[8192] / hist u32[4096]
  __shared__ u32 s_comp[4096];           // 16 KB ; later: s_t u16[8064] / depth u16[4096]+parent u16[4096]
  __shared__ unsigned char s_mst[NE];    // 8 KB  ; bit0 = tree edge
  __shared__ volatile int s_flag;
  __shared__ volatile u32 s_maxd;

  u32* arr    = (u32*)s_best;             // 8192 u32 (32 KB)
  short* pfx  = (short*)s_best;           // 8192 short (first 16 KB)
  u16* s_t    = (u16*)s_comp;             // 8064 u16
  u16* s_dep  = (u16*)s_comp;             // final: 4096 u16
  u16* s_parr = ((u16*)s_comp) + 4096;    // final: 4096 u16
  u32* cnt32  = (u32*)s_best;             // final hist: 4096 u32 (first 16 KB)

  u64 mykey[8];
  #pragma unroll
  for (int k=0;k<8;++k){ int e = tid + (k<<10); mykey[k] = (e < NE) ? keys[b*NE + e] : ~0ull; }

  for (int i=tid;i<4096;i+=1024){ s_comp[i] = i; lmin_g[b*4096+i] = 0x7FFFFFFF; }
  for (int e=tid;e<NE;e+=1024) s_mst[e] = 0;
  __syncthreads();

  // ---- Boruvka rounds (winner-flag early exit) ----
  for (int round=0; round<14; ++round){
    for (int i=tid;i<4096;i+=1024) s_best[i] = ~0ull;
    if (tid==0) s_flag = 0;
    __syncthreads();
    #pragma unroll
    for (int k=0;k<8;++k){
      int e = tid + (k<<10);
      if (e < NE){
        int u,v; edge_uv(e,u,v);
        u32 ru = s_comp[u], rv = s_comp[v];
        if (ru != rv){
          amin64(&s_best[ru], mykey[k]);
          amin64(&s_best[rv], mykey[k]);
        }
      }
    }
    __syncthreads();
    u32 np4[4]; int any = 0;
    #pragma unroll
    for (int t=0;t<4;++t){
      int i = tid + (t<<10);
      np4[t] = s_comp[i];
      if (s_comp[i] == (u32)i && s_best[i] != ~0ull){
        int e = (int)(s_best[i] & 0x1FFFull);
        int u,v; edge_uv(e,u,v);
        u32 ru = s_comp[u], rv = s_comp[v];
        u32 s = (ru == (u32)i) ? rv : ru;
        s_mst[e] = 1; any = 1;
        bool mutual = ((s_best[s] & 0x1FFFull) == (u64)e);
        if (!mutual || (u32)i > s) np4[t] = s;   // mutual pair: smaller id stays root
      }
    }
    if (any) s_flag = 1;
    __syncthreads();
    int fl = s_flag;
    #pragma unroll
    for (int t=0;t<4;++t){ int i = tid + (t<<10); s_comp[i] = np4[t]; }
    __syncthreads();
    if (!fl) break;
    // pointer jumping until flat
    for (int pass=0; pass<14; ++pass){
      if (tid==0) s_flag = 0;
      __syncthreads();
      u32 t4[4]; int ch = 0;
      #pragma unroll
      for (int t=0;t<4;++t){
        int i = tid + (t<<10);
        u32 a = s_comp[i]; u32 na = s_comp[a];
        t4[t] = na; if (na != a) ch = 1;
      }
      __syncthreads();
      #pragma unroll
      for (int t=0;t<4;++t){ int i = tid + (t<<10); s_comp[i] = t4[t]; }
      if (ch) s_flag = 1;
      __syncthreads();
      int fl2 = s_flag;
      __syncthreads();
      if (!fl2) break;
    }
  }

  // ---- Euler tour: compact arc ids via prefix-sum of tree-edge flags ----
  for (int i=tid;i<8192;i+=1024) arr[i] = (i<NE && s_mst[i]) ? 1u : 0u;
  __syncthreads();
  for (int off=1; off<8192; off<<=1){
    u32 t8[8];
    #pragma unroll
    for (int k=0;k<8;++k){ int i=tid+(k<<10); t8[k] = (i>=off)? arr[i-off] : 0u; }
    __syncthreads();
    #pragma unroll
    for (int k=0;k<8;++k){ int i=tid+(k<<10); arr[i] += t8[k]; }
    __syncthreads();
  }
  for (int e=tid;e<NE;e+=1024) s_t[e] = (u16)(arr[e] - (s_mst[e]?1u:0u));
  __syncthreads();

  // successor of arc (w->v): next outgoing arc of v after (v->w) in fixed dir order; cut at root 0
  auto nextarc = [&](int v, int w) -> int {
    int nb[4], eg[4]; int deg=0;
    int r=v>>6, c=v&63;
    if (c>0  && (s_mst[r*63+c-1]&1)){ nb[deg]=v-1;  eg[deg]=r*63+c-1; ++deg; }
    if (c<63 && (s_mst[r*63+c]&1))  { nb[deg]=v+1;  eg[deg]=r*63+c;   ++deg; }
    if (r>0  && (s_mst[NEH+v-64]&1)){ nb[deg]=v-64; eg[deg]=NEH+v-64; ++deg; }
    if (r<63 && (s_mst[NEH+v]&1))  { nb[deg]=v+64; eg[deg]=NEH+v;    ++deg; }
    int j=0;
    for (int k2=0;k2<deg;++k2) if (nb[k2]==w) j=k2;
    int jn=j+1;
    if (jn==deg){ if (v==0) return SENT; jn=0; }
    int e2=eg[jn], w2=nb[jn];
    return 2*(int)s_t[e2] + ((v<w2)?0:1);
  };

  // build packed (succ<<16)|dist; non-tree arcs self-loop with dist 0
  __syncthreads();
  for (int i=tid;i<8192;i+=1024) arr[i] = ((u32)i << 16);
  __syncthreads();
  for (int e=tid;e<NE;e+=1024){
    if (s_mst[e]&1){
      int t=s_t[e], u,v; edge_uv(e,u,v);
      arr[2*t]   = ((u32)nextarc(v,u) << 16) | 1u;   // arc u->v (head v)
      arr[2*t+1] = ((u32)nextarc(u,v) << 16) | 1u;   // arc v->u (head u)
    }
  }
  __syncthreads();

  // Wyllie (single pass, packed): dist-to-end in low 16, succ in high 16
  u32 reg8[8];
  #pragma unroll
  for (int k=0;k<8;++k) reg8[k] = arr[tid+(k<<10)];
  for (int rd=0; rd<13; ++rd){
    u32 o8[8];
    #pragma unroll
    for (int k=0;k<8;++k) o8[k] = arr[reg8[k] >> 16];
    __syncthreads();
    #pragma unroll
    for (int k=0;k<8;++k){
      reg8[k] = (o8[k] & 0xFFFF0000u) | ((reg8[k] + o8[k]) & 0xFFFFu);
      arr[tid+(k<<10)] = reg8[k];
    }
    __syncthreads();
  }

  // per-edge: down-arc = earlier in tour (larger dist); positions pos = m - dist
  const int m = 8190;
  u32 pk[8]; int has[8];
  #pragma unroll
  for (int k=0;k<8;++k){
    int e = tid + (k<<10); has[k] = 0;
    if (e < NE && (s_mst[e]&1)){
      int t = s_t[e];
      int d0 = (int)(arr[2*t] & 0xFFFFu), d1 = (int)(arr[2*t+1] & 0xFFFFu);
      int down = (d0 > d1) ? 1 : 0;               // 1: arc (u->v) is the down arc
      int posD = m - (down ? d0 : d1);
      int posU = m - (down ? d1 : d0);
      pk[k] = (u32)posD | ((u32)posU << 13) | ((u32)down << 26);
      has[k] = 1;
    }
  }
  __syncthreads();   // all reads of arr done before scatter overwrites region

  // scatter +/-1 by tour position into short[8192]; positions 0..8189 covered bijectively
  if (tid < 2) pfx[8190 + tid] = 0;
  #pragma unroll
  for (int k=0;k<8;++k){
    if (has[k]){
      pfx[pk[k] & 0x1FFFu] = 1;
      pfx[(pk[k] >> 13) & 0x1FFFu] = -1;
    }
  }
  __syncthreads();
  // Hillis-Steele inclusive scan over short[8192] (sequential addressing)
  for (int off=1; off<8192; off<<=1){
    short t8[8];
    #pragma unroll
    for (int k=0;k<8;++k){ int i=tid+(k<<10); t8[k] = (i>=off) ? pfx[i-off] : (short)0; }
    __syncthreads();
    #pragma unroll
    for (int k=0;k<8;++k){ int i=tid+(k<<10); pfx[i] = (short)(pfx[i] + t8[k]); }
    __syncthreads();
  }

  // depth[child] = inclusive prefix at down-arc position; parent from orientation
  int chld[8], prnt[8], dpv[8];
  #pragma unroll
  for (int k=0;k<8;++k){
    int e = tid + (k<<10); chld[k] = -1;
    if (has[k]){
      int u,v; edge_uv(e,u,v);
      int down = (pk[k] >> 26) & 1;
      chld[k] = down ? v : u;
      prnt[k] = down ? u : v;
      dpv[k]  = (int)pfx[pk[k] & 0x1FFFu];
    }
  }
  __syncthreads();   // all reads of s_t/pfx done before overwriting s_comp region
  #pragma unroll
  for (int k=0;k<8;++k) if (chld[k]>=0){ s_dep[chld[k]]=(u16)dpv[k]; s_parr[chld[k]]=(u16)prnt[k]; }
  if (tid==0){ s_dep[0]=0; s_parr[0]=0; }
  __syncthreads();

  // ---- level histogram + min-node + scan + level-ordered meta scatter ----
  for (int i=tid;i<4096;i+=1024) cnt32[i] = 0;
  if (tid==0) s_maxd = 0;
  __syncthreads();
  #pragma unroll
  for (int t=0;t<4;++t){
    int i = (tid<<2) + t;
    u32 dd = s_dep[i];
    atomicAdd(&cnt32[dd], 1u);
    atomicMax((u32*)&s_maxd, dd);
    atomicMin(&lmin_g[b*4096 + (int)dd], i);
  }
  __syncthreads();
  int md = (int)s_maxd;
  for (int off=1; off<4096; off<<=1){
    u32 t4[4];
    #pragma unroll
    for (int t=0;t<4;++t){ int i = tid + (t<<10); t4[t] = (i>=off) ? cnt32[i-off] : 0u; }
    __syncthreads();
    #pragma unroll
    for (int t=0;t<4;++t){ int i = tid + (t<<10); cnt32[i] += t4[t]; }
    __syncthreads();
  }
  for (int i=tid; i<4097; i+=1024){
    int ls = (i==0) ? 0 : (int)cnt32[i-1];
    level_start_g[b*4104 + i] = ls;
  }
  u32 ex4[4];
  #pragma unroll
  for (int t=0;t<4;++t){ int i = tid + (t<<10); ex4[t] = (i==0) ? 0u : cnt32[i-1]; }
  __syncthreads();
  #pragma unroll
  for (int t=0;t<4;++t){ int i = tid + (t<<10); cnt32[i] = ex4[t]; }
  __syncthreads();
  #pragma unroll
  for (int t=0;t<4;++t){
    int i = (tid<<2) + t;
    u32 pos = atomicAdd(&cnt32[s_dep[i]], 1u);
    meta_g[b*4096 + (int)pos] = i | ((int)s_parr[i] << 16);        // v | parent<<16, level-ordered
    meta2_g[b*4096 + (int)pos] = s_parr[s_parr[i]];                // grandparent; pad_p bit set by k5b
  }
  if (tid==0) maxd_g[b] = md;
}

// ---------------- K5b: mark pad-keepers (meta bit12) and their children (meta2 bit12) ----------------
__global__ __launch_bounds__(256) void k5b_mark(const int* __restrict__ lstart, const int* __restrict__ lmin_g,
                                                int* __restrict__ meta_g, u16* __restrict__ meta2_g){
  int d = blockIdx.x*256 + threadIdx.x;
  if (d == 0 || d >= 4096) return;
  int cnts[NB]; int mx = 0;
  #pragma unroll
  for (int b=0;b<NB;++b){
    int c = lstart[b*4104 + d + 1] - lstart[b*4104 + d];
    cnts[b] = c; if (c > mx) mx = c;
  }
  #pragma unroll
  for (int b=0;b<NB;++b){
    if (cnts[b] > 0 && cnts[b] < mx){
      int keeper = lmin_g[b*4096 + d];
      int st = lstart[b*4104 + d];
      for (int p2=st; p2<st+cnts[b]; ++p2){
        int idx = b*4096 + p2;
        if ((meta_g[idx] & 4095) == keeper){ meta_g[idx] |= 0x1000; break; }
      }
      // children of keeper live at level d+1: mark their meta2 pad_p bit
      if (d + 1 < 4096){
        int st1 = lstart[b*4104 + d + 1], en1 = lstart[b*4104 + d + 2];
        for (int p2=st1; p2<en1; ++p2){
          int idx = b*4096 + p2;
          if (((meta_g[idx] >> 16) & 4095) == keeper) meta2_g[idx] |= 0x1000;
        }
      }
    }
  }
}

// ---------------- K5c: permute ew into LEVEL order (in place) + elp = ew[parent] (into gbuf) ----------------
__global__ __launch_bounds__(256) void k5c_permute(const int* __restrict__ meta_g, float* __restrict__ ew_cm,
                                                   float* __restrict__ elp_out){
  __shared__ float se[4096];
  const int bid = blockIdx.x;
  const int b = bid / ND, ch = bid - b*ND;
  float* ewc = ew_cm  + ((size_t)(b*ND + ch))*NL;
  float* ep  = elp_out + ((size_t)(b*ND + ch))*NL;
  const int* mg = meta_g + b*4096;
  for (int i=threadIdx.x; i<1024; i+=256) ((float4*)se)[i] = ((const float4*)ewc)[i];
  __syncthreads();
  for (int p=threadIdx.x; p<NL; p+=256){
    int m = mg[p];
    ewc[p] = se[m & 4095];
    ep[p]  = se[(m >> 16) & 4095];
  }
}

// ---------------- K6: LDS-resident tree scan, 2-level fused periods (half the fences) ----------------
// up: level-d nodes scatter w*u to parent AND wp*w*u to grandparent; level-(d-1) nodes scatter wp*bx self-term.
// down: level-(d+1) nodes recompute parent's aggr from grandparent. Reads precede writes in program order
// (single wave => LDS ops retire in issue order). Pairs wider than 64 fall back to classic 2-step.
__global__ __launch_bounds__(64) void k6_scan(const float* __restrict__ el_cm, const float* __restrict__ elp_cm,
                                              const float* __restrict__ up_cm, float* __restrict__ aggr_cm,
                                              const int* __restrict__ meta_g, const u16* __restrict__ meta2_g,
                                              const int* __restrict__ lstart, const int* __restrict__ maxd_g){
  __shared__ float s_ua[4096];      // BX -> up -> aggr (in-place)
  __shared__ u16   s_ls[4100];      // level starts
  const int bid = blockIdx.x;
  const int b = bid / ND, ch = bid - b*ND;
  const int lane = threadIdx.x;
  const int md = maxd_g[b];
  const float* el  = el_cm  + ((size_t)(b*ND + ch))*NL;   // ew, level order
  const float* elp = elp_cm + ((size_t)(b*ND + ch))*NL;   // ew of parent, level order
  const float* upc = up_cm  + ((size_t)(b*ND + ch))*NL;
  const int* mg  = meta_g  + b*4096;
  const u16* m2g = meta2_g + b*4096;

  for (int i=lane; i<1024; i+=64) ((float4*)s_ua)[i] = ((const float4*)upc)[i];
  for (int i=lane; i<=md+1; i+=64) s_ls[i] = (u16)lstart[b*4104 + i];
  lds_fence_wave();

  // ===== up-sweep: fused pairs {d, d-1}, d = md, md-2, ... ; leftover single level {1} if d reaches 1 =====
  {
    int d = md;
    int lo, mid, hi;
    if (d >= 2){ lo = s_ls[d-1]; mid = s_ls[d]; hi = s_ls[d+1]; }
    else       { lo = s_ls[1];   mid = s_ls[2]; hi = s_ls[2];   }   // leftover: all "B" (no gp)
    int m0=0; u16 mm0=0; float w0=0.f, wp0=0.f;
    if (lane < hi-lo){ int p=lo+lane; m0=mg[p]; mm0=m2g[p]; w0=el[p]; wp0=elp[p]; }
    while (d >= 1){
      int dn = d - 2;
      int lo2=0, mid2=0, hi2=0;
      int m1=0; u16 mm1=0; float w1=0.f, wp1=0.f;
      if (dn >= 1){
        if (dn >= 2){ lo2 = s_ls[dn-1]; mid2 = s_ls[dn]; hi2 = s_ls[dn+1]; }
        else        { lo2 = s_ls[1];    mid2 = s_ls[2];  hi2 = s_ls[2];    }
        if (lane < hi2-lo2){ int p=lo2+lane; m1=mg[p]; mm1=m2g[p]; w1=el[p]; wp1=elp[p]; }
      }
      int tot = hi - lo;
      if (tot <= 64){
        if (lane < tot){
          int own = m0 & 4095, par = (m0 >> 16) & 4095;
          float val = s_ua[own];
          compiler_fence();
          float contrib = w0 * val;
          atomicAdd(&s_ua[par], contrib);
          if (lo + lane >= mid) atomicAdd(&s_ua[mm0 & 4095], wp0 * contrib);
        }
      } else {
        // fallback: classic 2 steps (level d = [mid,hi), then level d-1 = [lo,mid))
        for (int i=mid+lane; i<hi; i+=64){
          int m = mg[i]; float w = el[i];
          atomicAdd(&s_ua[(m>>16)&4095], w * s_ua[m&4095]);
        }
        lds_fence_wave();
        for (int i=lo+lane; i<mid; i+=64){
          int m = mg[i]; float w = el[i];
          atomicAdd(&s_ua[(m>>16)&4095], w * s_ua[m&4095]);
        }
      }
      lds_fence_wave();
      d = dn; lo=lo2; mid=mid2; hi=hi2; m0=m1; mm0=mm1; w0=w1; wp0=wp1;
    }
  }

  // ===== down-sweep: fused pairs {d, d+1}, d = 1, 3, ... ; leftover single {md} if md odd =====
  if (md >= 1){
    int d = 1;
    int lo, mid, hi;
    if (d+1 <= md){ lo = s_ls[d]; mid = s_ls[d+1]; hi = s_ls[d+2]; }
    else          { lo = s_ls[d]; mid = s_ls[d+1]; hi = s_ls[d+1]; }  // leftover: all A
    int m0=0; u16 mm0=0; float w0=0.f, wp0=0.f;
    if (lane < hi-lo){ int p=lo+lane; m0=mg[p]; mm0=m2g[p]; w0=el[p]; wp0=elp[p]; }
    while (d <= md){
      int dn = d + 2;
      int lo2=0, mid2=0, hi2=0;
      int m1=0; u16 mm1=0; float w1=0.f, wp1=0.f;
      if (dn <= md){
        if (dn+1 <= md){ lo2 = s_ls[dn]; mid2 = s_ls[dn+1]; hi2 = s_ls[dn+2]; }
        else           { lo2 = s_ls[dn]; mid2 = s_ls[dn+1]; hi2 = s_ls[dn+1]; }
        if (lane < hi2-lo2){ int p=lo2+lane; m1=mg[p]; mm1=m2g[p]; w1=el[p]; wp1=elp[p]; }
      }
      int tot = hi - lo;
      if (tot <= 64){
        if (lane < tot){
          bool isB = (lo + lane >= mid);
          int own = m0 & 4095, par = (m0 >> 16) & 4095;
          float u_own = s_ua[own];
          float x_par = s_ua[par];            // A: aggr[p] (final); B: u_v (pristine this period)
          float a_g = 0.f;
          if (isB) a_g = s_ua[mm0 & 4095];    // grandparent aggr (final)
          compiler_fence();
          float a_par;
          if (isB){
            float uv = x_par;
            a_par = (mm0 & 0x1000) ? uv : uv + wp0*(a_g - wp0*uv);
          } else {
            a_par = x_par;
          }
          float res = (m0 & 0x1000) ? u_own : u_own + w0*(a_par - w0*u_own);
          s_ua[own] = res;
        }
      } else {
        // fallback: classic 2 steps (level d = [lo,mid), then level d+1 = [mid,hi))
        for (int i=lo+lane; i<mid; i+=64){
          int m = mg[i]; float w = el[i];
          float u = s_ua[m & 4095];
          float ap = s_ua[(m>>16) & 4095];
          float r = (m & 0x1000) ? u : u + w*(ap - w*u);
          s_ua[m & 4095] = r;
        }
        lds_fence_wave();
        for (int i=mid+lane; i<hi; i+=64){
          int m = mg[i]; float w = el[i];
          float u = s_ua[m & 4095];
          float ap = s_ua[(m>>16) & 4095];
          float r = (m & 0x1000) ? u : u + w*(ap - w*u);
          s_ua[m & 4095] = r;
        }
      }
      lds_fence_wave();
      d = dn; lo=lo2; mid=mid2; hi=hi2; m0=m1; mm0=mm1; w0=w1; wp0=wp1;
    }
  }
  lds_fence_wave();
  // write back CHANNEL-MAJOR (overwrites the elp region for this (b,ch) -- all elp reads are done)
  float* outc = aggr_cm + ((size_t)(b*ND + ch))*NL;
  for (int i=lane; i<1024; i+=64) ((float4*)outc)[i] = ((const float4*)s_ua)[i];
}

// ---------------- K7: LN(h)*Cs + Ds*xs -> LN -> *z ; aggr read CM via LDS transpose tile ----------------
__global__ __launch_bounds__(256) void k7_norm(const float* __restrict__ aggr_cm, const float* __restrict__ xs,
                                               const float* __restrict__ z, const float* __restrict__ Cs,
                                               const float* __restrict__ Dsw, const float* __restrict__ hg,
                                               const float* __restrict__ hb, const float* __restrict__ og,
                                               const float* __restrict__ ob, float* __restrict__ yfin){
  __shared__ float tile[192*33];    // [ch][lcol], pad 33 -> LN-phase reads are 2-way (free)
  const int b  = blockIdx.x >> 7;          // 8 batches
  const int l0 = (blockIdx.x & 127) * 32;  // 128 tiles of 32 l-values
  const int tid = threadIdx.x;

  for (int i=tid; i<192*32; i+=256){
    int ch = i >> 5, lcol = i & 31;
    tile[ch*33 + lcol] = aggr_cm[((size_t)(b*ND + ch))*NL + l0 + lcol];
  }
  __syncthreads();

  const int wv = tid >> 6, lane = tid & 63;
  for (int s=0; s<8; ++s){
    int lcol = wv*8 + s;
    int gid = b*NL + l0 + lcol;
    float h[3], x3[3], z3[3];
    #pragma unroll
    for (int j=0;j<3;++j){
      int d = lane + 64*j;
      h[j]  = tile[d*33 + lcol];
      x3[j] = xs[(size_t)gid*ND + d];
      z3[j] = z[(size_t)gid*ND + d];
    }
    float mu  = wred_f(h[0]+h[1]+h[2]) / 192.f;
    float vs = 0.f;
    #pragma unroll
    for (int j=0;j<3;++j){ float t = h[j]-mu; vs += t*t; }
    float inv = 1.f / sqrtf(wred_f(vs)/192.f + 1e-5f);
    float Cv = Cs[gid];
    float y[3];
    #pragma unroll
    for (int j=0;j<3;++j){
      int d = lane + 64*j;
      float hn = (h[j]-mu)*inv*hg[d] + hb[d];
      y[j] = hn*Cv + Dsw[d]*x3[j];
    }
    float mu2 = wred_f(y[0]+y[1]+y[2]) / 192.f;
    float vs2 = 0.f;
    #pragma unroll
    for (int j=0;j<3;++j){ float t = y[j]-mu2; vs2 += t*t; }
    float inv2 = 1.f / sqrtf(wred_f(vs2)/192.f + 1e-5f);
    #pragma unroll
    for (int j=0;j<3;++j){
      int d = lane + 64*j;
      float o = (y[j]-mu2)*inv2*og[d] + ob[d];
      yfin[(size_t)gid*ND + d] = o*z3[j];
    }
  }
}

// ---------------- K8: out = yfin @ out_proj_w.T (f32, LDS-tiled, K split 2x96 sequential) ----------------
__global__ __launch_bounds__(256) void k8_out(const float* __restrict__ yfin, const float* __restrict__ w2,
                                              float* __restrict__ out){
  __shared__ float sy[96*33];       // [k][row0..31], pad 33
  __shared__ float sw[96*97];       // [k][o0..95], pad 97
  const int tid = threadIdx.x;
  const int row0 = blockIdx.x * 32;
  const int rq = tid >> 5;          // 0..7 -> rows rq*4..rq*4+3
  const int cq = tid & 31;          // 0..31 -> cols cq*3..cq*3+2
  float acc[4][3];
  #pragma unroll
  for (int a=0;a<4;++a)
    #pragma unroll
    for (int bcl=0;bcl<3;++bcl) acc[a][bcl] = 0.f;

  for (int kc=0; kc<2; ++kc){
    __syncthreads();
    for (int i=tid; i<32*96; i+=256){
      int r = i/96, k = i - r*96;
      sy[k*33 + r] = yfin[(size_t)(row0+r)*ND + kc*96 + k];
    }
    for (int i=tid; i<96*96; i+=256){
      int o = i/96, k = i - o*96;
      sw[k*97 + o] = w2[(size_t)o*ND + kc*96 + k];
    }
    __syncthreads();
    #pragma unroll 4
    for (int k=0;k<96;++k){
      float4 ya = *(const float4*)&sy[k*33 + rq*4];
      float w0 = sw[k*97 + cq*3 + 0];
      float w1 = sw[k*97 + cq*3 + 1];
      float wv = sw[k*97 + cq*3 + 2];
      acc[0][0] += ya.x*w0; acc[0][1] += ya.x*w1; acc[0][2] += ya.x*wv;
      acc[1][0] += ya.y*w0; acc[1][1] += ya.y*w1; acc[1][2] += ya.y*wv;
      acc[2][0] += ya.z*w0; acc[2][1] += ya.z*w1; acc[2][2] += ya.z*wv;
      acc[3][0] += ya.w*w0; acc[3][1] += ya.w*w1; acc[3][2] += ya.w*wv;
    }
  }

  #pragma unroll
  for (int a=0;a<4;++a){
    size_t row = row0 + rq*4 + a;
    #pragma unroll
    for (int bcl=0;bcl<3;++bcl){
      out[row*NDM + cq*3 + bcl] = acc[a][bcl];
    }
  }
}

extern "C" void kernel_launch(void* const* d_in, const int* in_sizes, int n_in,
                              void* d_out, int out_size, void* d_ws, size_t ws_size,
                              hipStream_t stream){
  const float* x    = (const float*)d_in[0];
  const float* inw  = (const float*)d_in[1];
  const float* cw   = (const float*)d_in[2];
  const float* cb   = (const float*)d_in[3];
  const float* xpw  = (const float*)d_in[4];
  const float* dtw  = (const float*)d_in[5];
  const float* dtb  = (const float*)d_in[6];
  const float* alog = (const float*)d_in[7];
  const float* Dsw  = (const float*)d_in[8];
  const float* hg   = (const float*)d_in[9];
  const float* hb   = (const float*)d_in[10];
  const float* og   = (const float*)d_in[11];
  const float* ob   = (const float*)d_in[12];
  const float* w2   = (const float*)d_in[13];
  float* out = (float*)d_out;

  const size_t S = (size_t)NB*NL*ND;   // 6,291,456 elems per f32 buffer
  float* bufA  = (float*)d_ws;         // xc_pre; reused as yfin after k2
  float* bufZ  = bufA + S;             // silu(z)
  float* bufX  = bufZ + S;             // xs (post-conv silu)
  float* ew_cm = bufX + S;             // deltaA, channel-major; k5c permutes to LEVEL order in place
  float* up_cm = ew_cm + S;            // BX, channel-major [b][d][l]
  float* bufG  = up_cm + S;            // elp stream (k5c) -> overwritten with aggr by k6
  char* q = (char*)(bufG + S);
  double* norms = (double*)q;                q += (size_t)NB*NL*sizeof(double);
  u64* keys     = (u64*)q;                   q += (size_t)NB*NE*sizeof(u64);
  float* Cs     = (float*)q;                 q += (size_t)NB*NL*sizeof(float);
  int* lstart   = (int*)q;                   q += (size_t)NB*4104*sizeof(int);
  int* maxd     = (int*)q;                   q += 64*sizeof(int);
  int* lmin     = (int*)q;                   q += (size_t)NB*NL*sizeof(int);
  int* meta     = (int*)q;                   q += (size_t)NB*NL*sizeof(int);
  u16* meta2    = (u16*)q;                   q += (size_t)NB*NL*sizeof(u16);
  float* yfin   = bufA;                      // reuse (xc_pre dead after k2)

  k1_inproj<<<dim3(NB*NL/32*4), dim3(256), 0, stream>>>(x, inw, bufA, bufZ);
  k2_conv  <<<dim3((NB*NL*ND)/256), dim3(256), 0, stream>>>(bufA, cw, cb, bufX);
  k3_ssm   <<<dim3(NB*NL/4), dim3(256), 0, stream>>>(bufX, xpw, dtw, dtb, alog, ew_cm, up_cm, Cs, norms);
  k4_keys  <<<dim3(NB*NE/4), dim3(256), 0, stream>>>(bufX, norms, keys);
  k5_tree  <<<dim3(NB), dim3(1024), 0, stream>>>(keys, meta, meta2, lstart, maxd, lmin);
  k5b_mark <<<dim3(16), dim3(256), 0, stream>>>(lstart, lmin, meta, meta2);
  k5c_permute<<<dim3(NB*ND), dim3(256), 0, stream>>>(meta, ew_cm, bufG);
  k6_scan  <<<dim3(NB*ND), dim3(64), 0, stream>>>(ew_cm, bufG, up_cm, bufG, meta, meta2, lstart, maxd);
  k7_norm  <<<dim3(NB*128), dim3(256), 0, stream>>>(bufG, bufX, bufZ, Cs, Dsw, hg, hb, og, ob, yfin);
  k8_out   <<<dim3(NB*NL/32), dim3(256), 0, stream>>>(yfin, w2, out);
}

// Round 13
// 684.152 us; speedup vs baseline: 1.1235x; 1.1235x over previous
//
#include <hip/hip_runtime.h>
#include <hip/hip_bf16.h>
#include <cstdint>

typedef unsigned long long u64;
typedef unsigned int u32;
typedef unsigned short u16;

constexpr int NB   = 8;     // batch
constexpr int NL   = 4096;  // H*W
constexpr int ND   = 192;   // D_INNER
constexpr int NDM  = 96;    // D_MODEL
constexpr int NE   = 8064;  // edges per batch
constexpr int NEH  = 4032;  // horizontal edges
constexpr int SENT = 8190;  // Euler sentinel (m = 2*4095)

__device__ __forceinline__ float siluf(float x){ return x / (1.f + expf(-x)); }
__device__ __forceinline__ float softplusf(float x){ return fmaxf(x,0.f) + log1pf(expf(-fabsf(x))); }

// single-wave LDS-only fence: wave LDS ops complete in order; drain lgkm + compiler barrier.
__device__ __forceinline__ void lds_fence_wave(){
  asm volatile("s_waitcnt lgkmcnt(0)" ::: "memory");
}

__device__ __forceinline__ float wred_f(float v){
  #pragma unroll
  for (int o=32;o;o>>=1) v += __shfl_down(v,o);
  return __shfl(v,0);
}
__device__ __forceinline__ double wred_d(double v){
  #pragma unroll
  for (int o=32;o;o>>=1) v += __shfl_down(v,o);
  return __shfl(v,0);
}

// edge e -> endpoints (reference ordering: horizontal first, row-major, then vertical); u < v always
__device__ __forceinline__ void edge_uv(int e, int& u, int& v){
  if (e < NEH){ int r=e/63; int c=e-r*63; u=(r<<6)+c; v=u+1; }
  else        { u=e-NEH; v=u+64; }
}

__device__ __forceinline__ void amin64(u64* addr, u64 val){
  u64 old = *addr;
  while (val < old){
    u64 assumed = old;
    old = atomicCAS(addr, assumed, val);
    if (old == assumed) break;
  }
}

// ---------------- K1: xz = x @ in_proj_w.T (f32, LDS-tiled); split -> xc_pre, z=silu ----------------
__global__ __launch_bounds__(256) void k1_inproj(const float* __restrict__ x, const float* __restrict__ w,
                                                 float* __restrict__ xc_pre, float* __restrict__ zb){
  __shared__ float sx[96*33];       // [k][row0..31], pad 33
  __shared__ float sw[96*97];       // [k][col0..95], pad 97
  const int tid = threadIdx.x;
  const int brow = blockIdx.x >> 2;
  const int cc   = blockIdx.x & 3;
  const int row0 = brow * 32;
  {
    const float* src = x + (size_t)row0*96;
    for (int i=tid; i<32*96; i+=256){
      int r = i/96, k = i - r*96;
      sx[k*33 + r] = src[i];
    }
  }
  {
    const float* src = w + (size_t)cc*96*96;
    for (int i=tid; i<96*96; i+=256){
      int c = i/96, k = i - c*96;
      sw[k*97 + c] = src[i];
    }
  }
  __syncthreads();
  const int rq = tid >> 5;
  const int cq = tid & 31;
  float acc[4][3];
  #pragma unroll
  for (int a=0;a<4;++a)
    #pragma unroll
    for (int bcl=0;bcl<3;++bcl) acc[a][bcl] = 0.f;
  #pragma unroll 4
  for (int k=0;k<96;++k){
    float4 xa = *(const float4*)&sx[k*33 + rq*4];
    float w0 = sw[k*97 + cq*3 + 0];
    float w1 = sw[k*97 + cq*3 + 1];
    float w2 = sw[k*97 + cq*3 + 2];
    acc[0][0] += xa.x*w0; acc[0][1] += xa.x*w1; acc[0][2] += xa.x*w2;
    acc[1][0] += xa.y*w0; acc[1][1] += xa.y*w1; acc[1][2] += xa.y*w2;
    acc[2][0] += xa.z*w0; acc[2][1] += xa.z*w1; acc[2][2] += xa.z*w2;
    acc[3][0] += xa.w*w0; acc[3][1] += xa.w*w1; acc[3][2] += xa.w*w2;
  }
  #pragma unroll
  for (int a=0;a<4;++a){
    size_t row = row0 + rq*4 + a;
    #pragma unroll
    for (int bcl=0;bcl<3;++bcl){
      int c = cq*3 + bcl;
      float v = acc[a][bcl];
      if (cc < 2) xc_pre[row*ND + cc*96 + c] = v;
      else        zb[row*ND + (cc-2)*96 + c] = siluf(v);
    }
  }
}

// ---------------- K2: depthwise 3x3 conv (SAME) + bias + silu (f32) -> xs ----------------
__global__ __launch_bounds__(256) void k2_conv(const float* __restrict__ xc_pre, const float* __restrict__ cw,
                                               const float* __restrict__ cb, float* __restrict__ xs){
  int idx = blockIdx.x*256 + threadIdx.x;
  if (idx >= NB*NL*ND) return;
  int d = idx % ND;
  int l = (idx/ND) & 4095;
  int b = idx / (ND*NL);
  int r = l >> 6, c = l & 63;
  float acc = cb[d];
  #pragma unroll
  for (int dy=-1; dy<=1; ++dy){
    int rr = r+dy; if (rr<0 || rr>63) continue;
    #pragma unroll
    for (int dx=-1; dx<=1; ++dx){
      int cc = c+dx; if (cc<0 || cc>63) continue;
      acc += xc_pre[((size_t)b*NL + (rr<<6) + cc)*ND + d] * cw[d*9 + (dy+1)*3 + (dx+1)];
    }
  }
  xs[idx] = siluf(acc);
}

// ---------------- K3: x_dbl dots, dts->softplus, ew/BX written CHANNEL-MAJOR, Cs, f64 norms ----------------
__global__ __launch_bounds__(256) void k3_ssm(const float* __restrict__ xs, const float* __restrict__ xpw,
                                              const float* __restrict__ dtw, const float* __restrict__ dtb,
                                              const float* __restrict__ alog,
                                              float* __restrict__ ew_cm, float* __restrict__ up_cm,
                                              float* __restrict__ Cs, double* __restrict__ norms){
  int gid = blockIdx.x*4 + (threadIdx.x>>6);   // one wave per (b,l)
  if (gid >= NB*NL) return;
  int lane = threadIdx.x & 63;
  int b = gid >> 12, l = gid & 4095;
  const float* xr = xs + (size_t)gid*ND;
  float xv[3];
  #pragma unroll
  for (int j=0;j<3;++j) xv[j] = xr[lane + 64*j];
  float sums[8];
  #pragma unroll
  for (int cc=0; cc<8; ++cc){
    float p = 0.f;
    #pragma unroll
    for (int j=0;j<3;++j) p += xv[j]*xpw[cc*ND + lane + 64*j];
    sums[cc] = wred_f(p);
  }
  double n2 = 0.0;
  #pragma unroll
  for (int j=0;j<3;++j) n2 += (double)xv[j]*(double)xv[j];
  n2 = wred_d(n2);
  if (lane==0){
    Cs[gid] = sums[7];
    norms[gid] = fmax(sqrt(n2), 1e-8);
  }
  float Bv = sums[6];
  #pragma unroll
  for (int j=0;j<3;++j){
    int d = lane + 64*j;
    float dtv = dtb[d];
    #pragma unroll
    for (int r=0;r<6;++r) dtv += sums[r]*dtw[d*6+r];
    float sp = softplusf(dtv);
    float A  = -expf(alog[d]);
    size_t o = ((size_t)(b*ND + d))*NL + l;      // channel-major
    ew_cm[o] = expf(sp*A);
    up_cm[o] = sp*Bv*xv[j];   // BX = dts*Bs*xs
  }
}

// ---------------- K4: per-edge f64 normalized dot -> sortable u64 key ----------------
__global__ __launch_bounds__(256) void k4_keys(const float* __restrict__ xs, const double* __restrict__ norms,
                                               u64* __restrict__ keys){
  int gid = blockIdx.x*4 + (threadIdx.x>>6);   // one wave per (b,e)
  if (gid >= NB*NE) return;
  int lane = threadIdx.x & 63;
  int b = gid / NE, e = gid - b*NE;
  int u, v; edge_uv(e, u, v);
  const float* xu = xs + ((size_t)(b*NL + u))*ND;
  const float* xw = xs + ((size_t)(b*NL + v))*ND;
  double nu = norms[b*NL+u], nv = norms[b*NL+v];
  double dot = 0.0;
  #pragma unroll
  for (int j=0;j<3;++j){
    int d = lane + 64*j;
    double du = (double)xu[d] / nu;     // fn = f/norm per element, like reference
    double dv = (double)xw[d] / nv;
    dot += du*dv;
  }
  dot = wred_d(dot);
  if (lane==0){
    long long q = __double2ll_rn((1.0 - dot) * 17592186044416.0);  // 2^44
    if (q < 0) q = 0;
    keys[gid] = (((u64)q) << 13) | (u64)e;
  }
}

// ---------------- K5: Boruvka MST + Euler-tour depth/parent (single Wyllie + positional scan) ----------------
__global__ __launch_bounds__(1024) void k5_tree(const u64* __restrict__ keys,
                                                int* __restrict__ meta_g, int* __restrict__ level_start_g,
                                                int* __restrict__ maxd_g, int* __restrict__ lmin_g){
  const int b = blockIdx.x;
  const int tid = threadIdx.x;
  __shared__ u64 s_best[4096];           // 32 KB ; later: arr u32[8192] (packed succ|dist) / pfx short[8192] / hist u32[4096]
  __shared__ u32 s_comp[4096];           // 16 KB ; later: s_t u16[8064] / depth u16[4096]+parent u16[4096]
  __shared__ unsigned char s_mst[NE];    // 8 KB  ; bit0 = tree edge
  __shared__ volatile int s_flag;
  __shared__ volatile u32 s_maxd;

  u32* arr    = (u32*)s_best;             // 8192 u32 (32 KB)
  short* pfx  = (short*)s_best;           // 8192 short (first 16 KB)
  u16* s_t    = (u16*)s_comp;             // 8064 u16
  u16* s_dep  = (u16*)s_comp;             // final: 4096 u16
  u16* s_parr = ((u16*)s_comp) + 4096;    // final: 4096 u16
  u32* cnt32  = (u32*)s_best;             // final hist: 4096 u32 (first 16 KB)

  u64 mykey[8];
  #pragma unroll
  for (int k=0;k<8;++k){ int e = tid + (k<<10); mykey[k] = (e < NE) ? keys[b*NE + e] : ~0ull; }

  for (int i=tid;i<4096;i+=1024){ s_comp[i] = i; lmin_g[b*4096+i] = 0x7FFFFFFF; }
  for (int e=tid;e<NE;e+=1024) s_mst[e] = 0;
  __syncthreads();

  // ---- Boruvka rounds (winner-flag early exit) ----
  for (int round=0; round<14; ++round){
    for (int i=tid;i<4096;i+=1024) s_best[i] = ~0ull;
    if (tid==0) s_flag = 0;
    __syncthreads();
    #pragma unroll
    for (int k=0;k<8;++k){
      int e = tid + (k<<10);
      if (e < NE){
        int u,v; edge_uv(e,u,v);
        u32 ru = s_comp[u], rv = s_comp[v];
        if (ru != rv){
          amin64(&s_best[ru], mykey[k]);
          amin64(&s_best[rv], mykey[k]);
        }
      }
    }
    __syncthreads();
    u32 np4[4]; int any = 0;
    #pragma unroll
    for (int t=0;t<4;++t){
      int i = tid + (t<<10);
      np4[t] = s_comp[i];
      if (s_comp[i] == (u32)i && s_best[i] != ~0ull){
        int e = (int)(s_best[i] & 0x1FFFull);
        int u,v; edge_uv(e,u,v);
        u32 ru = s_comp[u], rv = s_comp[v];
        u32 s = (ru == (u32)i) ? rv : ru;
        s_mst[e] = 1; any = 1;
        bool mutual = ((s_best[s] & 0x1FFFull) == (u64)e);
        if (!mutual || (u32)i > s) np4[t] = s;   // mutual pair: smaller id stays root
      }
    }
    if (any) s_flag = 1;
    __syncthreads();
    int fl = s_flag;
    #pragma unroll
    for (int t=0;t<4;++t){ int i = tid + (t<<10); s_comp[i] = np4[t]; }
    __syncthreads();
    if (!fl) break;
    // pointer jumping until flat
    for (int pass=0; pass<14; ++pass){
      if (tid==0) s_flag = 0;
      __syncthreads();
      u32 t4[4]; int ch = 0;
      #pragma unroll
      for (int t=0;t<4;++t){
        int i = tid + (t<<10);
        u32 a = s_comp[i]; u32 na = s_comp[a];
        t4[t] = na; if (na != a) ch = 1;
      }
      __syncthreads();
      #pragma unroll
      for (int t=0;t<4;++t){ int i = tid + (t<<10); s_comp[i] = t4[t]; }
      if (ch) s_flag = 1;
      __syncthreads();
      int fl2 = s_flag;
      __syncthreads();
      if (!fl2) break;
    }
  }

  // ---- Euler tour: compact arc ids via prefix-sum of tree-edge flags ----
  for (int i=tid;i<8192;i+=1024) arr[i] = (i<NE && s_mst[i]) ? 1u : 0u;
  __syncthreads();
  for (int off=1; off<8192; off<<=1){
    u32 t8[8];
    #pragma unroll
    for (int k=0;k<8;++k){ int i=tid+(k<<10); t8[k] = (i>=off)? arr[i-off] : 0u; }
    __syncthreads();
    #pragma unroll
    for (int k=0;k<8;++k){ int i=tid+(k<<10); arr[i] += t8[k]; }
    __syncthreads();
  }
  for (int e=tid;e<NE;e+=1024) s_t[e] = (u16)(arr[e] - (s_mst[e]?1u:0u));
  __syncthreads();

  // successor of arc (w->v): next outgoing arc of v after (v->w) in fixed dir order; cut at root 0
  auto nextarc = [&](int v, int w) -> int {
    int nb[4], eg[4]; int deg=0;
    int r=v>>6, c=v&63;
    if (c>0  && (s_mst[r*63+c-1]&1)){ nb[deg]=v-1;  eg[deg]=r*63+c-1; ++deg; }
    if (c<63 && (s_mst[r*63+c]&1))  { nb[deg]=v+1;  eg[deg]=r*63+c;   ++deg; }
    if (r>0  && (s_mst[NEH+v-64]&1)){ nb[deg]=v-64; eg[deg]=NEH+v-64; ++deg; }
    if (r<63 && (s_mst[NEH+v]&1))  { nb[deg]=v+64; eg[deg]=NEH+v;    ++deg; }
    int j=0;
    for (int k2=0;k2<deg;++k2) if (nb[k2]==w) j=k2;
    int jn=j+1;
    if (jn==deg){ if (v==0) return SENT; jn=0; }
    int e2=eg[jn], w2=nb[jn];
    return 2*(int)s_t[e2] + ((v<w2)?0:1);
  };

  // build packed (succ<<16)|dist; non-tree arcs self-loop with dist 0
  __syncthreads();
  for (int i=tid;i<8192;i+=1024) arr[i] = ((u32)i << 16);
  __syncthreads();
  for (int e=tid;e<NE;e+=1024){
    if (s_mst[e]&1){
      int t=s_t[e], u,v; edge_uv(e,u,v);
      arr[2*t]   = ((u32)nextarc(v,u) << 16) | 1u;   // arc u->v (head v)
      arr[2*t+1] = ((u32)nextarc(u,v) << 16) | 1u;   // arc v->u (head u)
    }
  }
  __syncthreads();

  // Wyllie (single pass, packed): dist-to-end in low 16, succ in high 16
  u32 reg8[8];
  #pragma unroll
  for (int k=0;k<8;++k) reg8[k] = arr[tid+(k<<10)];
  for (int rd=0; rd<13; ++rd){
    u32 o8[8];
    #pragma unroll
    for (int k=0;k<8;++k) o8[k] = arr[reg8[k] >> 16];
    __syncthreads();
    #pragma unroll
    for (int k=0;k<8;++k){
      reg8[k] = (o8[k] & 0xFFFF0000u) | ((reg8[k] + o8[k]) & 0xFFFFu);
      arr[tid+(k<<10)] = reg8[k];
    }
    __syncthreads();
  }

  // per-edge: down-arc = earlier in tour (larger dist); positions pos = m - dist
  const int m = 8190;
  u32 pk[8]; int has[8];
  #pragma unroll
  for (int k=0;k<8;++k){
    int e = tid + (k<<10); has[k] = 0;
    if (e < NE && (s_mst[e]&1)){
      int t = s_t[e];
      int d0 = (int)(arr[2*t] & 0xFFFFu), d1 = (int)(arr[2*t+1] & 0xFFFFu);
      int down = (d0 > d1) ? 1 : 0;               // 1: arc (u->v) is the down arc
      int posD = m - (down ? d0 : d1);
      int posU = m - (down ? d1 : d0);
      pk[k] = (u32)posD | ((u32)posU << 13) | ((u32)down << 26);
      has[k] = 1;
    }
  }
  __syncthreads();   // all reads of arr done before scatter overwrites region

  // scatter +/-1 by tour position into short[8192]; positions 0..8189 covered bijectively
  if (tid < 2) pfx[8190 + tid] = 0;
  #pragma unroll
  for (int k=0;k<8;++k){
    if (has[k]){
      pfx[pk[k] & 0x1FFFu] = 1;
      pfx[(pk[k] >> 13) & 0x1FFFu] = -1;
    }
  }
  __syncthreads();
  // Hillis-Steele inclusive scan over short[8192] (sequential addressing)
  for (int off=1; off<8192; off<<=1){
    short t8[8];
    #pragma unroll
    for (int k=0;k<8;++k){ int i=tid+(k<<10); t8[k] = (i>=off) ? pfx[i-off] : (short)0; }
    __syncthreads();
    #pragma unroll
    for (int k=0;k<8;++k){ int i=tid+(k<<10); pfx[i] = (short)(pfx[i] + t8[k]); }
    __syncthreads();
  }

  // depth[child] = inclusive prefix at down-arc position; parent from orientation
  int chld[8], prnt[8], dpv[8];
  #pragma unroll
  for (int k=0;k<8;++k){
    int e = tid + (k<<10); chld[k] = -1;
    if (has[k]){
      int u,v; edge_uv(e,u,v);
      int down = (pk[k] >> 26) & 1;
      chld[k] = down ? v : u;
      prnt[k] = down ? u : v;
      dpv[k]  = (int)pfx[pk[k] & 0x1FFFu];
    }
  }
  __syncthreads();   // all reads of s_t/pfx done before overwriting s_comp region
  #pragma unroll
  for (int k=0;k<8;++k) if (chld[k]>=0){ s_dep[chld[k]]=(u16)dpv[k]; s_parr[chld[k]]=(u16)prnt[k]; }
  if (tid==0){ s_dep[0]=0; s_parr[0]=0; }
  __syncthreads();

  // ---- level histogram + min-node + scan + level-ordered meta scatter ----
  for (int i=tid;i<4096;i+=1024) cnt32[i] = 0;
  if (tid==0) s_maxd = 0;
  __syncthreads();
  #pragma unroll
  for (int t=0;t<4;++t){
    int i = (tid<<2) + t;
    u32 dd = s_dep[i];
    atomicAdd(&cnt32[dd], 1u);
    atomicMax((u32*)&s_maxd, dd);
    atomicMin(&lmin_g[b*4096 + (int)dd], i);
  }
  __syncthreads();
  int md = (int)s_maxd;
  for (int off=1; off<4096; off<<=1){
    u32 t4[4];
    #pragma unroll
    for (int t=0;t<4;++t){ int i = tid + (t<<10); t4[t] = (i>=off) ? cnt32[i-off] : 0u; }
    __syncthreads();
    #pragma unroll
    for (int t=0;t<4;++t){ int i = tid + (t<<10); cnt32[i] += t4[t]; }
    __syncthreads();
  }
  for (int i=tid; i<4097; i+=1024){
    int ls = (i==0) ? 0 : (int)cnt32[i-1];
    level_start_g[b*4104 + i] = ls;
  }
  u32 ex4[4];
  #pragma unroll
  for (int t=0;t<4;++t){ int i = tid + (t<<10); ex4[t] = (i==0) ? 0u : cnt32[i-1]; }
  __syncthreads();
  #pragma unroll
  for (int t=0;t<4;++t){ int i = tid + (t<<10); cnt32[i] = ex4[t]; }
  __syncthreads();
  #pragma unroll
  for (int t=0;t<4;++t){
    int i = (tid<<2) + t;
    u32 pos = atomicAdd(&cnt32[s_dep[i]], 1u);
    meta_g[b*4096 + (int)pos] = i | ((int)s_parr[i] << 16);   // v | parent<<16, level-ordered
  }
  if (tid==0) maxd_g[b] = md;
}

// ---------------- K5b: mark pad-keeper nodes: bit 12 of meta on the lmin node of padded levels ----------------
__global__ __launch_bounds__(256) void k5b_mark(const int* __restrict__ lstart, const int* __restrict__ lmin_g,
                                                int* __restrict__ meta_g){
  int d = blockIdx.x*256 + threadIdx.x;
  if (d == 0 || d >= 4096) return;
  int cnts[NB]; int mx = 0;
  #pragma unroll
  for (int b=0;b<NB;++b){
    int c = lstart[b*4104 + d + 1] - lstart[b*4104 + d];
    cnts[b] = c; if (c > mx) mx = c;
  }
  #pragma unroll
  for (int b=0;b<NB;++b){
    if (cnts[b] > 0 && cnts[b] < mx){
      int keeper = lmin_g[b*4096 + d];
      int st = lstart[b*4104 + d];
      for (int p2=st; p2<st+cnts[b]; ++p2){
        int idx = b*4096 + p2;
        if ((meta_g[idx] & 4095) == keeper){ meta_g[idx] |= 0x1000; break; }
      }
    }
  }
}

// ---------------- K5c: permute ew into LEVEL order per (b,ch), in place via LDS staging ----------------
__global__ __launch_bounds__(256) void k5c_permute(const int* __restrict__ meta_g, float* __restrict__ ew_cm){
  __shared__ float se[4096];
  const int bid = blockIdx.x;
  const int b = bid / ND, ch = bid - b*ND;
  float* ewc = ew_cm + ((size_t)(b*ND + ch))*NL;
  const int* mg = meta_g + b*4096;
  for (int i=threadIdx.x; i<1024; i+=256) ((float4*)se)[i] = ((const float4*)ewc)[i];
  __syncthreads();
  for (int p=threadIdx.x; p<NL; p+=256) ewc[p] = se[mg[p] & 4095];
}

// ---------------- K6: LDS-resident tree scan, one wave per (batch, channel); CM output ----------------
// Two independent streams (meta, level-ordered ew) software-pipelined 2 levels deep; two levels per iter.
__global__ __launch_bounds__(64) void k6_scan(const float* __restrict__ ewlo_cm, const float* __restrict__ up_cm,
                                              float* __restrict__ aggr_cm, const int* __restrict__ meta_g,
                                              const int* __restrict__ lstart, const int* __restrict__ maxd_g){
  __shared__ float s_ua[4096];      // BX -> up -> aggr (in-place)
  __shared__ u16   s_ls[4100];      // level starts
  const int bid = blockIdx.x;
  const int b = bid / ND, ch = bid - b*ND;
  const int lane = threadIdx.x;
  const int md = maxd_g[b];
  const float* el = ewlo_cm + ((size_t)(b*ND + ch))*NL;   // ew in LEVEL order
  const float* upc = up_cm + ((size_t)(b*ND + ch))*NL;
  const int* mg = meta_g + b*4096;

  for (int i=lane; i<1024; i+=64) ((float4*)s_ua)[i] = ((const float4*)upc)[i];
  for (int i=lane; i<=md+1; i+=64) s_ls[i] = (u16)lstart[b*4104 + i];
  lds_fence_wave();

  // ---- up-sweep: levels md..1, two per iteration, loads issued 2 levels ahead ----
  {
    int stA = s_ls[md], cA = (int)s_ls[md+1] - stA;
    int stB = 0, cB = 0;
    if (md >= 2){ stB = s_ls[md-1]; cB = (int)s_ls[md] - stB; }
    int mA=0, mB=0; float wA=0.f, wB=0.f;
    if (lane < cA){ mA = mg[stA+lane]; wA = el[stA+lane]; }
    if (lane < cB){ mB = mg[stB+lane]; wB = el[stB+lane]; }
    for (int d = md; d >= 1; d -= 2){
      int stA2=0,cA2=0,mA2=0, stB2=0,cB2=0,mB2=0; float wA2=0.f, wB2=0.f;
      if (d >= 3){ stA2 = s_ls[d-2]; cA2 = (int)s_ls[d-1]-stA2; if (lane<cA2){ mA2 = mg[stA2+lane]; wA2 = el[stA2+lane]; } }
      if (d >= 4){ stB2 = s_ls[d-3]; cB2 = (int)s_ls[d-2]-stB2; if (lane<cB2){ mB2 = mg[stB2+lane]; wB2 = el[stB2+lane]; } }
      for (int i=lane; i<cA; i+=64){
        int m; float w;
        if (i == lane){ m = mA; w = wA; } else { m = mg[stA+i]; w = el[stA+i]; }
        int v = m & 4095, p = (m >> 16) & 4095;
        atomicAdd(&s_ua[p], w * s_ua[v]);
      }
      lds_fence_wave();
      if (d >= 2){
        for (int i=lane; i<cB; i+=64){
          int m; float w;
          if (i == lane){ m = mB; w = wB; } else { m = mg[stB+i]; w = el[stB+i]; }
          int v = m & 4095, p = (m >> 16) & 4095;
          atomicAdd(&s_ua[p], w * s_ua[v]);
        }
        lds_fence_wave();
      }
      stA=stA2; cA=cA2; mA=mA2; wA=wA2;
      stB=stB2; cB=cB2; mB=mB2; wB=wB2;
    }
  }
  // ---- down-sweep: levels 1..md, same pipelining; pad keeper via bit 12 of meta ----
  {
    int stA = s_ls[1], cA = (int)s_ls[2] - stA;
    int stB = 0, cB = 0;
    if (md >= 2){ stB = s_ls[2]; cB = (int)s_ls[3] - stB; }
    int mA=0, mB=0; float wA=0.f, wB=0.f;
    if (lane < cA){ mA = mg[stA+lane]; wA = el[stA+lane]; }
    if (lane < cB){ mB = mg[stB+lane]; wB = el[stB+lane]; }
    for (int d = 1; d <= md; d += 2){
      int stA2=0,cA2=0,mA2=0, stB2=0,cB2=0,mB2=0; float wA2=0.f, wB2=0.f;
      if (d+2 <= md){ stA2 = s_ls[d+2]; cA2 = (int)s_ls[d+3]-stA2; if (lane<cA2){ mA2 = mg[stA2+lane]; wA2 = el[stA2+lane]; } }
      if (d+3 <= md){ stB2 = s_ls[d+3]; cB2 = (int)s_ls[d+4]-stB2; if (lane<cB2){ mB2 = mg[stB2+lane]; wB2 = el[stB2+lane]; } }
      for (int i=lane; i<cA; i+=64){
        int m; float w;
        if (i == lane){ m = mA; w = wA; } else { m = mg[stA+i]; w = el[stA+i]; }
        int v = m & 4095, p = (m >> 16) & 4095;
        float uv = s_ua[v], pa = s_ua[p];
        float res = uv + w*(pa - w*uv);
        if (m & 0x1000) res = uv;      // duplicate-scatter pad: old (up-sweep) value wins
        s_ua[v] = res;
      }
      lds_fence_wave();
      if (d+1 <= md){
        for (int i=lane; i<cB; i+=64){
          int m; float w;
          if (i == lane){ m = mB; w = wB; } else { m = mg[stB+i]; w = el[stB+i]; }
          int v = m & 4095, p = (m >> 16) & 4095;
          float uv = s_ua[v], pa = s_ua[p];
          float res = uv + w*(pa - w*uv);
          if (m & 0x1000) res = uv;
          s_ua[v] = res;
        }
        lds_fence_wave();
      }
      stA=stA2; cA=cA2; mA=mA2; wA=wA2;
      stB=stB2; cB=cB2; mB=mB2; wB=wB2;
    }
  }
  lds_fence_wave();
  // write back CHANNEL-MAJOR: contiguous 16 KB per block, float4, fully coalesced full lines
  float* outc = aggr_cm + ((size_t)(b*ND + ch))*NL;
  for (int i=lane; i<1024; i+=64) ((float4*)outc)[i] = ((const float4*)s_ua)[i];
}

// ---------------- K7+K8 fused: LN(h)*Cs + Ds*xs -> LN -> *z -> GEMM @ out_proj_w.T ----------------
// y tile goes back into the SAME LDS slot as the h tile (identical [d][lcol] layout), then
// k8's exact 2x96-chunk GEMM runs from LDS -> bit-identical accumulation order, no yfin round-trip.
__global__ __launch_bounds__(256) void k7k8(const float* __restrict__ aggr_cm, const float* __restrict__ xs,
                                            const float* __restrict__ z, const float* __restrict__ Cs,
                                            const float* __restrict__ Dsw, const float* __restrict__ hg,
                                            const float* __restrict__ hb, const float* __restrict__ og,
                                            const float* __restrict__ ob, const float* __restrict__ w2,
                                            float* __restrict__ out){
  __shared__ float tile[192*33];    // phase1: h [d][lcol]; phase2: y [k][row] (same layout)
  __shared__ float sw[96*97];       // w2 chunk transposed [k][o0..95]
  const int b  = blockIdx.x >> 7;          // 8 batches
  const int l0 = (blockIdx.x & 127) * 32;  // 128 tiles of 32 rows
  const int tid = threadIdx.x;

  for (int i=tid; i<192*32; i+=256){
    int ch = i >> 5, lcol = i & 31;
    tile[ch*33 + lcol] = aggr_cm[((size_t)(b*ND + ch))*NL + l0 + lcol];
  }
  __syncthreads();

  const int wv = tid >> 6, lane = tid & 63;
  float yv[8][3];
  for (int s=0; s<8; ++s){
    int lcol = wv*8 + s;
    int gid = b*NL + l0 + lcol;
    float h[3], x3[3], z3[3];
    #pragma unroll
    for (int j=0;j<3;++j){
      int d = lane + 64*j;
      h[j]  = tile[d*33 + lcol];
      x3[j] = xs[(size_t)gid*ND + d];
      z3[j] = z[(size_t)gid*ND + d];
    }
    float mu  = wred_f(h[0]+h[1]+h[2]) / 192.f;
    float vs = 0.f;
    #pragma unroll
    for (int j=0;j<3;++j){ float t = h[j]-mu; vs += t*t; }
    float inv = 1.f / sqrtf(wred_f(vs)/192.f + 1e-5f);
    float Cv = Cs[gid];
    float y[3];
    #pragma unroll
    for (int j=0;j<3;++j){
      int d = lane + 64*j;
      float hn = (h[j]-mu)*inv*hg[d] + hb[d];
      y[j] = hn*Cv + Dsw[d]*x3[j];
    }
    float mu2 = wred_f(y[0]+y[1]+y[2]) / 192.f;
    float vs2 = 0.f;
    #pragma unroll
    for (int j=0;j<3;++j){ float t = y[j]-mu2; vs2 += t*t; }
    float inv2 = 1.f / sqrtf(wred_f(vs2)/192.f + 1e-5f);
    #pragma unroll
    for (int j=0;j<3;++j){
      int d = lane + 64*j;
      float o = (y[j]-mu2)*inv2*og[d] + ob[d];
      yv[s][j] = o*z3[j];
    }
  }
  __syncthreads();             // all h reads done
  #pragma unroll
  for (int s=0; s<8; ++s){
    int lcol = wv*8 + s;
    #pragma unroll
    for (int j=0;j<3;++j){
      int d = lane + 64*j;
      tile[d*33 + lcol] = yv[s][j];   // y into same slot/layout
    }
  }

  // ---- GEMM phase: out[32 x 96] = y[32 x 192] @ w2^T, K split 2x96 (bit-identical to old k8) ----
  const int rq = tid >> 5;          // 0..7 -> rows rq*4..rq*4+3
  const int cq = tid & 31;          // 0..31 -> cols cq*3..cq*3+2
  float acc[4][3];
  #pragma unroll
  for (int a=0;a<4;++a)
    #pragma unroll
    for (int bcl=0;bcl<3;++bcl) acc[a][bcl] = 0.f;

  for (int kc=0; kc<2; ++kc){
    __syncthreads();
    for (int i=tid; i<96*96; i+=256){
      int o = i/96, k = i - o*96;
      sw[k*97 + o] = w2[(size_t)o*ND + kc*96 + k];
    }
    __syncthreads();
    #pragma unroll 4
    for (int k=0;k<96;++k){
      float4 ya = *(const float4*)&tile[(kc*96 + k)*33 + rq*4];
      float w0 = sw[k*97 + cq*3 + 0];
      float w1 = sw[k*97 + cq*3 + 1];
      float wvv = sw[k*97 + cq*3 + 2];
      acc[0][0] += ya.x*w0; acc[0][1] += ya.x*w1; acc[0][2] += ya.x*wvv;
      acc[1][0] += ya.y*w0; acc[1][1] += ya.y*w1; acc[1][2] += ya.y*wvv;
      acc[2][0] += ya.z*w0; acc[2][1] += ya.z*w1; acc[2][2] += ya.z*wvv;
      acc[3][0] += ya.w*w0; acc[3][1] += ya.w*w1; acc[3][2] += ya.w*wvv;
    }
  }

  #pragma unroll
  for (int a=0;a<4;++a){
    size_t row = (size_t)b*NL + l0 + rq*4 + a;
    #pragma unroll
    for (int bcl=0;bcl<3;++bcl){
      out[row*NDM + cq*3 + bcl] = acc[a][bcl];
    }
  }
}

extern "C" void kernel_launch(void* const* d_in, const int* in_sizes, int n_in,
                              void* d_out, int out_size, void* d_ws, size_t ws_size,
                              hipStream_t stream){
  const float* x    = (const float*)d_in[0];
  const float* inw  = (const float*)d_in[1];
  const float* cw   = (const float*)d_in[2];
  const float* cb   = (const float*)d_in[3];
  const float* xpw  = (const float*)d_in[4];
  const float* dtw  = (const float*)d_in[5];
  const float* dtb  = (const float*)d_in[6];
  const float* alog = (const float*)d_in[7];
  const float* Dsw  = (const float*)d_in[8];
  const float* hg   = (const float*)d_in[9];
  const float* hb   = (const float*)d_in[10];
  const float* og   = (const float*)d_in[11];
  const float* ob   = (const float*)d_in[12];
  const float* w2   = (const float*)d_in[13];
  float* out = (float*)d_out;

  const size_t S = (size_t)NB*NL*ND;   // 6,291,456 elems per f32 buffer
  float* bufA  = (float*)d_ws;         // xc_pre
  float* bufZ  = bufA + S;             // silu(z)
  float* bufX  = bufZ + S;             // xs (post-conv silu)
  float* ew_cm = bufX + S;             // deltaA, channel-major; k5c permutes to LEVEL order in place
  float* up_cm = ew_cm + S;            // BX, channel-major [b][d][l]
  float* bufG  = up_cm + S;            // aggr, channel-major [b][d][l]
  char* q = (char*)(bufG + S);
  double* norms = (double*)q;                q += (size_t)NB*NL*sizeof(double);
  u64* keys     = (u64*)q;                   q += (size_t)NB*NE*sizeof(u64);
  float* Cs     = (float*)q;                 q += (size_t)NB*NL*sizeof(float);
  int* lstart   = (int*)q;                   q += (size_t)NB*4104*sizeof(int);
  int* maxd     = (int*)q;                   q += 64*sizeof(int);
  int* lmin     = (int*)q;                   q += (size_t)NB*NL*sizeof(int);
  int* meta     = (int*)q;                   q += (size_t)NB*NL*sizeof(int);

  k1_inproj<<<dim3(NB*NL/32*4), dim3(256), 0, stream>>>(x, inw, bufA, bufZ);
  k2_conv  <<<dim3((NB*NL*ND)/256), dim3(256), 0, stream>>>(bufA, cw, cb, bufX);
  k3_ssm   <<<dim3(NB*NL/4), dim3(256), 0, stream>>>(bufX, xpw, dtw, dtb, alog, ew_cm, up_cm, Cs, norms);
  k4_keys  <<<dim3(NB*NE/4), dim3(256), 0, stream>>>(bufX, norms, keys);
  k5_tree  <<<dim3(NB), dim3(1024), 0, stream>>>(keys, meta, lstart, maxd, lmin);
  k5b_mark <<<dim3(16), dim3(256), 0, stream>>>(lstart, lmin, meta);
  k5c_permute<<<dim3(NB*ND), dim3(256), 0, stream>>>(meta, ew_cm);
  k6_scan  <<<dim3(NB*ND), dim3(64), 0, stream>>>(ew_cm, up_cm, bufG, meta, lstart, maxd);
  k7k8     <<<dim3(NB*128), dim3(256), 0, stream>>>(bufG, bufX, bufZ, Cs, Dsw, hg, hb, og, ob, w2, out);
}